// Round 3
// baseline (763.599 us; speedup 1.0000x reference)
//
#include <hip/hip_runtime.h>
#include <cstdint>
#include <cstddef>

// Graph U-Net (no pooling), N=8192, D=256, L=3.
// R7 = R6 with compile fix: nontemporal builtins need native ext_vector types,
// not HIP_vector_type (float4/uint2). Logic identical to R6:
//   (1) k_spmm: one wave per row, 8B/lane gathers -> 512 B/wave covers the
//       whole 256-col row in ONE vmem instr (was 2 passes x 1 dword).
//       Halves VMEM requests, halves addr math, col list traversed once
//       (LDS-staged, ushort4 readback = 1 ds_read per 4 neighbors).
//   (2) Nontemporal loads/stores on all streaming traffic (col, y_bf, g,
//       skip bufs, fp32 outs) so L2 keeps only the 4 MB hs gather set.
//   (3) 2048 blocks = 8 blocks/CU = 32 waves/CU; unroll 8 with 8 loads in
//       flight, 2-deep split accumulators.

#define GN 8192
#define GD 256
#define CAP 320   // max degree capacity; max observed degree ~175

typedef unsigned int uint32;
using frag_ab = __attribute__((ext_vector_type(8))) short;   // 8 bf16
using frag_cd = __attribute__((ext_vector_type(4))) float;   // 4 fp32
using f32x4   = __attribute__((ext_vector_type(4))) float;   // nt-load friendly
using u32x2   = __attribute__((ext_vector_type(2))) uint32;  // nt-store friendly

// RNE float -> bf16 bits (values are finite; NaN path not needed)
static __device__ inline unsigned short f2bf(float x) {
    uint32 u = __float_as_uint(x);
    u += 0x7fffu + ((u >> 16) & 1u);
    return (unsigned short)(u >> 16);
}

// ---------------------------------------------------------------------------
// Kernel 1: build adjacency lists + dinv. One block per row.
// g is a 256 MB one-shot stream -> nontemporal loads; col writes nt too.
__global__ __launch_bounds__(256) void k_build(const float* __restrict__ g,
                                               unsigned short* __restrict__ col,
                                               int* __restrict__ cnt,
                                               float* __restrict__ dinv)
{
    __shared__ int s_cnt;
    const int i = blockIdx.x;
    const int tid = threadIdx.x;
    if (tid == 0) s_cnt = 0;
    __syncthreads();
    const f32x4* grow = (const f32x4*)(g + (size_t)i * GN);
    unsigned short* crow = col + (size_t)i * CAP;
    for (int j4 = tid; j4 < GN / 4; j4 += 256) {
        f32x4 v = __builtin_nontemporal_load(grow + j4);
        int j = j4 * 4;
        if (v[0] != 0.0f) { int p = atomicAdd(&s_cnt, 1); if (p < CAP) __builtin_nontemporal_store((unsigned short)(j + 0), crow + p); }
        if (v[1] != 0.0f) { int p = atomicAdd(&s_cnt, 1); if (p < CAP) __builtin_nontemporal_store((unsigned short)(j + 1), crow + p); }
        if (v[2] != 0.0f) { int p = atomicAdd(&s_cnt, 1); if (p < CAP) __builtin_nontemporal_store((unsigned short)(j + 2), crow + p); }
        if (v[3] != 0.0f) { int p = atomicAdd(&s_cnt, 1); if (p < CAP) __builtin_nontemporal_store((unsigned short)(j + 3), crow + p); }
    }
    __syncthreads();
    if (tid == 0) {
        int n = s_cnt; if (n > CAP) n = CAP;
        cnt[i] = n;
        dinv[i] = rsqrtf((float)s_cnt + 1.0f);
    }
}

// ---------------------------------------------------------------------------
// Kernel 2: hs_bf = bf16(dinv[:,None] * h)
__global__ __launch_bounds__(256) void k_scale(const float* __restrict__ h,
                                               const float* __restrict__ dinv,
                                               unsigned short* __restrict__ hs_bf)
{
    int idx = blockIdx.x * 256 + threadIdx.x;      // float4 index
    float4 v = ((const float4*)h)[idx];
    int row = idx / (GD / 4);
    float dv = dinv[row];
    ushort4 r;
    r.x = f2bf(v.x * dv); r.y = f2bf(v.y * dv);
    r.z = f2bf(v.z * dv); r.w = f2bf(v.w * dv);
    ((ushort4*)hs_bf)[idx] = r;
}

// ---------------------------------------------------------------------------
// Kernel 2b: generic fp32 -> bf16 convert (weights), n multiple of 1024
__global__ __launch_bounds__(256) void k_f2bf(const float* __restrict__ src,
                                              unsigned short* __restrict__ dst)
{
    int idx = blockIdx.x * 256 + threadIdx.x;      // float4 index
    float4 v = ((const float4*)src)[idx];
    ushort4 r;
    r.x = f2bf(v.x); r.y = f2bf(v.y); r.z = f2bf(v.z); r.w = f2bf(v.w);
    ((ushort4*)dst)[idx] = r;
}

// ---------------------------------------------------------------------------
// Kernel 3: SpMM. y_bf[i,:] = bf16(dinv[i]*(hs[i,:] + sum_n hs[n,:]))
// One wave per row; lane owns 8 B (4 bf16, elements 4l..4l+3).
// Per neighbor: 1 global_load_dwordx2 (wave = 512 B contiguous = full row),
// 8 VALU unpack-adds. col list staged in LDS (nt loads), read back ushort4.
// y stored nontemporal (pure stream). 2048 blocks -> 32 waves/CU.
__global__ __launch_bounds__(256) void k_spmm(const u32x2* __restrict__ hsw,
                                              const unsigned short* __restrict__ col,
                                              const int* __restrict__ cnt,
                                              const float* __restrict__ dinv,
                                              u32x2* __restrict__ yw)
{
    __shared__ unsigned short s_cols[4][CAP];
    const int tid  = threadIdx.x;
    const int lr   = tid >> 6;          // wave id = local row 0..3
    const int lane = tid & 63;
    const int i    = blockIdx.x * 4 + lr;
    const int n    = cnt[i];
    unsigned short* sc = s_cols[lr];
    const unsigned short* crow = col + (size_t)i * CAP;
    for (int t = lane; t < n; t += 64)
        sc[t] = __builtin_nontemporal_load(crow + t);
    // wave-coherent staging: producer == consumer wave; no barrier.

    float e0a = 0.f, e1a = 0.f, e2a = 0.f, e3a = 0.f;
    float e0b = 0.f, e1b = 0.f, e2b = 0.f, e3b = 0.f;
    int t = 0;
    for (; t + 8 <= n; t += 8) {
        ushort4 ca = *(const ushort4*)(sc + t);
        ushort4 cb = *(const ushort4*)(sc + t + 4);
        u32x2 u0 = hsw[(uint32)ca.x * 64u + lane];
        u32x2 u1 = hsw[(uint32)ca.y * 64u + lane];
        u32x2 u2 = hsw[(uint32)ca.z * 64u + lane];
        u32x2 u3 = hsw[(uint32)ca.w * 64u + lane];
        u32x2 u4 = hsw[(uint32)cb.x * 64u + lane];
        u32x2 u5 = hsw[(uint32)cb.y * 64u + lane];
        u32x2 u6 = hsw[(uint32)cb.z * 64u + lane];
        u32x2 u7 = hsw[(uint32)cb.w * 64u + lane];
        e0a += __uint_as_float(u0[0] << 16); e1a += __uint_as_float(u0[0] & 0xffff0000u);
        e2a += __uint_as_float(u0[1] << 16); e3a += __uint_as_float(u0[1] & 0xffff0000u);
        e0b += __uint_as_float(u1[0] << 16); e1b += __uint_as_float(u1[0] & 0xffff0000u);
        e2b += __uint_as_float(u1[1] << 16); e3b += __uint_as_float(u1[1] & 0xffff0000u);
        e0a += __uint_as_float(u2[0] << 16); e1a += __uint_as_float(u2[0] & 0xffff0000u);
        e2a += __uint_as_float(u2[1] << 16); e3a += __uint_as_float(u2[1] & 0xffff0000u);
        e0b += __uint_as_float(u3[0] << 16); e1b += __uint_as_float(u3[0] & 0xffff0000u);
        e2b += __uint_as_float(u3[1] << 16); e3b += __uint_as_float(u3[1] & 0xffff0000u);
        e0a += __uint_as_float(u4[0] << 16); e1a += __uint_as_float(u4[0] & 0xffff0000u);
        e2a += __uint_as_float(u4[1] << 16); e3a += __uint_as_float(u4[1] & 0xffff0000u);
        e0b += __uint_as_float(u5[0] << 16); e1b += __uint_as_float(u5[0] & 0xffff0000u);
        e2b += __uint_as_float(u5[1] << 16); e3b += __uint_as_float(u5[1] & 0xffff0000u);
        e0a += __uint_as_float(u6[0] << 16); e1a += __uint_as_float(u6[0] & 0xffff0000u);
        e2a += __uint_as_float(u6[1] << 16); e3a += __uint_as_float(u6[1] & 0xffff0000u);
        e0b += __uint_as_float(u7[0] << 16); e1b += __uint_as_float(u7[0] & 0xffff0000u);
        e2b += __uint_as_float(u7[1] << 16); e3b += __uint_as_float(u7[1] & 0xffff0000u);
    }
    for (; t < n; ++t) {
        u32x2 u = hsw[(uint32)sc[t] * 64u + lane];
        e0a += __uint_as_float(u[0] << 16); e1a += __uint_as_float(u[0] & 0xffff0000u);
        e2a += __uint_as_float(u[1] << 16); e3a += __uint_as_float(u[1] & 0xffff0000u);
    }
    u32x2 us = hsw[(uint32)i * 64u + lane];   // self-loop (+I)
    e0b += __uint_as_float(us[0] << 16); e1b += __uint_as_float(us[0] & 0xffff0000u);
    e2b += __uint_as_float(us[1] << 16); e3b += __uint_as_float(us[1] & 0xffff0000u);

    const float dv = dinv[i];
    const float e0 = (e0a + e0b) * dv;
    const float e1 = (e1a + e1b) * dv;
    const float e2 = (e2a + e2b) * dv;
    const float e3 = (e3a + e3b) * dv;
    u32x2 r;
    r[0] = (uint32)f2bf(e0) | ((uint32)f2bf(e1) << 16);
    r[1] = (uint32)f2bf(e2) | ((uint32)f2bf(e3) << 16);
    __builtin_nontemporal_store(r, yw + (uint32)i * 64u + lane);
}

// ---------------------------------------------------------------------------
// Kernel 4: MFMA bf16 linear layer. C = relu(Y @ W^T + b) with epilogues:
//   h_out  (fp32) : layer output (skip storage / final out slots)   [nt store]
//   hs_out (bf16) : bf16(dinv[m]*(v + skip)) — next SpMM input      [cached]
//   sum_out(fp32) : v + add_src (final h7 + org_h)                  [nt store]
// Y [8192][256] bf16 row-major; W [256][256] bf16 row-major ([out][in] -> B^T,
// K contiguous). Fragments loaded directly from global (16 B per lane), no LDS.
// Layouts (m89/m91-verified): A[m=lane&15][k=quad*8+j]; C/D row=quad*4+reg,
// col=lane&15.
__global__ __launch_bounds__(256) void k_gemm(const unsigned short* __restrict__ Y,
                                              const unsigned short* __restrict__ W,
                                              const float* __restrict__ bias,
                                              const float* __restrict__ dinv,
                                              const float* __restrict__ skip,
                                              float* __restrict__ h_out,
                                              unsigned short* __restrict__ hs_out,
                                              float* __restrict__ sum_out,
                                              const float* __restrict__ add_src)
{
    const int tid  = threadIdx.x;
    const int w    = tid >> 6;         // wave 0..3
    const int lane = tid & 63;
    const int quad = lane >> 4;
    const int l16  = lane & 15;
    const int m0 = blockIdx.x * 64 + w * 16;   // wave's 16 rows
    const int n0 = blockIdx.y * 64;            // block's 64 cols

    frag_cd acc0 = {0.f,0.f,0.f,0.f}, acc1 = {0.f,0.f,0.f,0.f};
    frag_cd acc2 = {0.f,0.f,0.f,0.f}, acc3 = {0.f,0.f,0.f,0.f};

    const size_t abase  = (size_t)(m0 + l16) * GD + quad * 8;
    const size_t bbase0 = (size_t)(n0 +  0 + l16) * GD + quad * 8;
    const size_t bbase1 = (size_t)(n0 + 16 + l16) * GD + quad * 8;
    const size_t bbase2 = (size_t)(n0 + 32 + l16) * GD + quad * 8;
    const size_t bbase3 = (size_t)(n0 + 48 + l16) * GD + quad * 8;

#pragma unroll
    for (int k0 = 0; k0 < GD; k0 += 32) {
        frag_ab a  = *(const frag_ab*)(Y + abase  + k0);
        frag_ab b0 = *(const frag_ab*)(W + bbase0 + k0);
        frag_ab b1 = *(const frag_ab*)(W + bbase1 + k0);
        frag_ab b2 = *(const frag_ab*)(W + bbase2 + k0);
        frag_ab b3 = *(const frag_ab*)(W + bbase3 + k0);
        acc0 = __builtin_amdgcn_mfma_f32_16x16x32_bf16(a, b0, acc0, 0, 0, 0);
        acc1 = __builtin_amdgcn_mfma_f32_16x16x32_bf16(a, b1, acc1, 0, 0, 0);
        acc2 = __builtin_amdgcn_mfma_f32_16x16x32_bf16(a, b2, acc2, 0, 0, 0);
        acc3 = __builtin_amdgcn_mfma_f32_16x16x32_bf16(a, b3, acc3, 0, 0, 0);
    }

    const float bn0 = bias[n0 +  0 + l16];
    const float bn1 = bias[n0 + 16 + l16];
    const float bn2 = bias[n0 + 32 + l16];
    const float bn3 = bias[n0 + 48 + l16];

#pragma unroll
    for (int reg = 0; reg < 4; ++reg) {
        const int m = m0 + quad * 4 + reg;
        const float dv = dinv[m];
        float v[4];
        v[0] = fmaxf(acc0[reg] + bn0, 0.f);
        v[1] = fmaxf(acc1[reg] + bn1, 0.f);
        v[2] = fmaxf(acc2[reg] + bn2, 0.f);
        v[3] = fmaxf(acc3[reg] + bn3, 0.f);
#pragma unroll
        for (int nt = 0; nt < 4; ++nt) {
            const size_t idx = (size_t)m * GD + n0 + nt * 16 + l16;
            const float x = v[nt];
            if (h_out)  __builtin_nontemporal_store(x, h_out + idx);
            if (hs_out) {
                float s = skip ? __builtin_nontemporal_load(skip + idx) : 0.f;
                hs_out[idx] = f2bf(dv * (x + s));
            }
            if (sum_out) __builtin_nontemporal_store(x + __builtin_nontemporal_load(add_src + idx), sum_out + idx);
        }
    }
}

// ---------------------------------------------------------------------------
extern "C" void kernel_launch(void* const* d_in, const int* in_sizes, int n_in,
                              void* d_out, int out_size, void* d_ws, size_t ws_size,
                              hipStream_t stream)
{
    const float* g  = (const float*)d_in[0];
    const float* h  = (const float*)d_in[1];
    const float* Wd = (const float*)d_in[2];
    const float* bd = (const float*)d_in[3];
    const float* Wb = (const float*)d_in[4];
    const float* bb = (const float*)d_in[5];
    const float* Wu = (const float*)d_in[6];
    const float* bu = (const float*)d_in[7];
    float* out = (float*)d_out;

    char* ws = (char*)d_ws;
    float*          dinv = (float*)ws;                               // 32 KB
    int*            cnt  = (int*)(ws + 32 * 1024);                   // 32 KB
    unsigned short* col  = (unsigned short*)(ws + 64 * 1024);        // 5.24 MB
    size_t off = 64 * 1024 + (size_t)GN * CAP * sizeof(unsigned short);
    off = (off + 255) & ~(size_t)255;
    unsigned short* hs_bf = (unsigned short*)(ws + off); off += (size_t)GN * GD * 2;  // 4 MB
    unsigned short* y_bf  = (unsigned short*)(ws + off); off += (size_t)GN * GD * 2;  // 4 MB
    unsigned short* w_bf  = (unsigned short*)(ws + off); off += (size_t)7 * GD * GD * 2; // 0.9 MB
    off = (off + 255) & ~(size_t)255;
    float* dbuf1 = (float*)(ws + off); off += (size_t)GN * GD * 4;   // 8 MB
    float* dbuf2 = (float*)(ws + off); off += (size_t)GN * GD * 4;   // 8 MB
    float* dbuf3 = (float*)(ws + off); off += (size_t)GN * GD * 4;   // 8 MB
    (void)ws_size; (void)in_sizes; (void)n_in; (void)out_size;

    const size_t ND = (size_t)GN * GD;
    const int WSZ = GD * GD;   // 65536 elements per weight matrix
    dim3 ggrid(GN / 64, GD / 64);

    k_build<<<GN, 256, 0, stream>>>(g, col, cnt, dinv);
    k_scale<<<GN * GD / 4 / 256, 256, 0, stream>>>(h, dinv, hs_bf);
    k_f2bf<<<3 * WSZ / 4 / 256, 256, 0, stream>>>(Wd, w_bf + 0 * (size_t)WSZ);
    k_f2bf<<<1 * WSZ / 4 / 256, 256, 0, stream>>>(Wb, w_bf + 3 * (size_t)WSZ);
    k_f2bf<<<3 * WSZ / 4 / 256, 256, 0, stream>>>(Wu, w_bf + 4 * (size_t)WSZ);

    // down 0..2: h_out -> dbuf, hs_out -> hs_bf (no skip)
    k_spmm<<<GN / 4, 256, 0, stream>>>((const u32x2*)hs_bf, col, cnt, dinv, (u32x2*)y_bf);
    k_gemm<<<ggrid, 256, 0, stream>>>(y_bf, w_bf + 0 * (size_t)WSZ, bd + 0 * GD, dinv, nullptr, dbuf1, hs_bf, nullptr, nullptr);
    k_spmm<<<GN / 4, 256, 0, stream>>>((const u32x2*)hs_bf, col, cnt, dinv, (u32x2*)y_bf);
    k_gemm<<<ggrid, 256, 0, stream>>>(y_bf, w_bf + 1 * (size_t)WSZ, bd + 1 * GD, dinv, nullptr, dbuf2, hs_bf, nullptr, nullptr);
    k_spmm<<<GN / 4, 256, 0, stream>>>((const u32x2*)hs_bf, col, cnt, dinv, (u32x2*)y_bf);
    k_gemm<<<ggrid, 256, 0, stream>>>(y_bf, w_bf + 2 * (size_t)WSZ, bd + 2 * GD, dinv, nullptr, dbuf3, hs_bf, nullptr, nullptr);

    // bottom: hs_out with skip = down_outs[2]
    k_spmm<<<GN / 4, 256, 0, stream>>>((const u32x2*)hs_bf, col, cnt, dinv, (u32x2*)y_bf);
    k_gemm<<<ggrid, 256, 0, stream>>>(y_bf, w_bf + 3 * (size_t)WSZ, bb, dinv, dbuf3, nullptr, hs_bf, nullptr, nullptr);

    // up 0: out[0] = h5; next hs with skip = down_outs[1]
    k_spmm<<<GN / 4, 256, 0, stream>>>((const u32x2*)hs_bf, col, cnt, dinv, (u32x2*)y_bf);
    k_gemm<<<ggrid, 256, 0, stream>>>(y_bf, w_bf + 4 * (size_t)WSZ, bu + 0 * GD, dinv, dbuf2, out + 0 * ND, hs_bf, nullptr, nullptr);
    // up 1: out[1] = h6; next hs with skip = down_outs[0]
    k_spmm<<<GN / 4, 256, 0, stream>>>((const u32x2*)hs_bf, col, cnt, dinv, (u32x2*)y_bf);
    k_gemm<<<ggrid, 256, 0, stream>>>(y_bf, w_bf + 5 * (size_t)WSZ, bu + 1 * GD, dinv, dbuf1, out + 1 * ND, hs_bf, nullptr, nullptr);
    // up 2: out[2] = h7; out[3] = h7 + org_h
    k_spmm<<<GN / 4, 256, 0, stream>>>((const u32x2*)hs_bf, col, cnt, dinv, (u32x2*)y_bf);
    k_gemm<<<ggrid, 256, 0, stream>>>(y_bf, w_bf + 6 * (size_t)WSZ, bu + 2 * GD, dinv, nullptr, out + 2 * ND, nullptr, out + 3 * ND, h);
}

// Round 5
// 759.639 us; speedup vs baseline: 1.0052x; 1.0052x over previous
//
#include <hip/hip_runtime.h>
#include <cstdint>
#include <cstddef>

// Graph U-Net (no pooling), N=8192, D=256, L=3.
// R9 = R8 with swizzle-read bug fix. 19 kernels -> 9.
//   (1) k_layer = fused spmm+gemm: per block, phase 1 aggregates 16 rows
//       (4 rows/wave, gather math identical to R7) into an XOR-swizzled
//       16x256 bf16 y-tile in LDS; barrier; phase 2 MFMAs y-tile x W.
//       y never touches global (-8MB roundtrip/layer, -7 launches).
//   (2) k_prep = fused h-scale + all weight bf16 converts (-4 launches).
//   (3) BUG FIX vs R8: swizzle XOR (r&7)<<4 flips byte bits 4-6; the read
//       must XOR the FULL offset (incl. k0*2, which carries bit 6+):
//       addr = (l16*512 + quad*16 + k0*2) ^ X, NOT (base^X) + k0*2.
//       R8 scrambled A/B K-pairing for rows with l16&4 (+1 OOB read).

#define GN 8192
#define GD 256
#define CAP 320   // max degree capacity; max observed degree ~175

typedef unsigned int uint32;
using frag_ab = __attribute__((ext_vector_type(8))) short;   // 8 bf16
using frag_cd = __attribute__((ext_vector_type(4))) float;   // 4 fp32
using u32x2   = __attribute__((ext_vector_type(2))) uint32;  // 8B gather unit

// RNE float -> bf16 bits (values are finite; NaN path not needed)
static __device__ inline unsigned short f2bf(float x) {
    uint32 u = __float_as_uint(x);
    u += 0x7fffu + ((u >> 16) & 1u);
    return (unsigned short)(u >> 16);
}

// ---------------------------------------------------------------------------
// Kernel 1: build adjacency lists + dinv. One block per row. (R5 version)
__global__ __launch_bounds__(256) void k_build(const float* __restrict__ g,
                                               unsigned short* __restrict__ col,
                                               int* __restrict__ cnt,
                                               float* __restrict__ dinv)
{
    __shared__ int s_cnt;
    const int i = blockIdx.x;
    const int tid = threadIdx.x;
    if (tid == 0) s_cnt = 0;
    __syncthreads();
    const float4* grow = (const float4*)(g + (size_t)i * GN);
    unsigned short* crow = col + (size_t)i * CAP;
    for (int j4 = tid; j4 < GN / 4; j4 += 256) {
        float4 v = grow[j4];
        int j = j4 * 4;
        if (v.x != 0.0f) { int p = atomicAdd(&s_cnt, 1); if (p < CAP) crow[p] = (unsigned short)(j + 0); }
        if (v.y != 0.0f) { int p = atomicAdd(&s_cnt, 1); if (p < CAP) crow[p] = (unsigned short)(j + 1); }
        if (v.z != 0.0f) { int p = atomicAdd(&s_cnt, 1); if (p < CAP) crow[p] = (unsigned short)(j + 2); }
        if (v.w != 0.0f) { int p = atomicAdd(&s_cnt, 1); if (p < CAP) crow[p] = (unsigned short)(j + 3); }
    }
    __syncthreads();
    if (tid == 0) {
        int n = s_cnt; if (n > CAP) n = CAP;
        cnt[i] = n;
        dinv[i] = rsqrtf((float)s_cnt + 1.0f);
    }
}

// ---------------------------------------------------------------------------
// Kernel 2: fused preprocessing.
//   blocks [0,2048):    hs = bf16(dinv[:,None] * h)        (2048*1024 elems)
//   blocks [2048,2240):  w_bf[0..3W)   = bf16(Wd)          (192 blocks)
//   blocks [2240,2304):  w_bf[3W..4W)  = bf16(Wb)          (64 blocks)
//   blocks [2304,2496):  w_bf[4W..7W)  = bf16(Wu)          (192 blocks)
__global__ __launch_bounds__(256) void k_prep(const float* __restrict__ h,
                                              const float* __restrict__ dinv,
                                              unsigned short* __restrict__ hs,
                                              const float* __restrict__ Wd,
                                              const float* __restrict__ Wb,
                                              const float* __restrict__ Wu,
                                              unsigned short* __restrict__ w_bf)
{
    const int WSZ = GD * GD;
    int bid = blockIdx.x;
    if (bid < 2048) {
        int idx = bid * 256 + threadIdx.x;      // float4 index
        float4 v = ((const float4*)h)[idx];
        int row = idx >> 6;                     // / (GD/4)
        float dv = dinv[row];
        ushort4 r;
        r.x = f2bf(v.x * dv); r.y = f2bf(v.y * dv);
        r.z = f2bf(v.z * dv); r.w = f2bf(v.w * dv);
        ((ushort4*)hs)[idx] = r;
        return;
    }
    bid -= 2048;
    const float* src;
    unsigned short* dst;
    if (bid < 192)      { src = Wd + (size_t)bid * 1024;        dst = w_bf + (size_t)bid * 1024; }
    else if (bid < 256) { src = Wb + (size_t)(bid - 192) * 1024; dst = w_bf + 3 * (size_t)WSZ + (size_t)(bid - 192) * 1024; }
    else                { src = Wu + (size_t)(bid - 256) * 1024; dst = w_bf + 4 * (size_t)WSZ + (size_t)(bid - 256) * 1024; }
    int t = threadIdx.x;
    float4 v = ((const float4*)src)[t];
    ushort4 r;
    r.x = f2bf(v.x); r.y = f2bf(v.y); r.z = f2bf(v.z); r.w = f2bf(v.w);
    ((ushort4*)dst)[t] = r;
}

// ---------------------------------------------------------------------------
// Kernel 3: fused GCN layer. For 16 rows per block:
//   phase 1: y[r,:] = bf16(dinv[r]*(hs[r,:] + sum_n hs[n,:]))  -> LDS (swizzled)
//   phase 2: C = relu(y @ W^T + b), epilogues:
//     h_out  (fp32) : layer output (skip storage / final out slots)
//     hs_out (bf16) : bf16(dinv[m]*(v + skip)) — next layer's hs (ping-pong)
//     sum_out(fp32) : v + add_src (final h7 + org_h)
// LDS swizzle: physical(logical byte L of row r) = L ^ ((r&7)<<4), applied to
// the FULL offset on both write (8B chunks, 8-aligned: XOR bits 4-6 keep the
// chunk contiguous) and read (16B frags, 16-aligned: ditto).
__global__ __launch_bounds__(256) void k_layer(const u32x2* __restrict__ hsw,
                                               const unsigned short* __restrict__ col,
                                               const int* __restrict__ cnt,
                                               const float* __restrict__ dinv,
                                               const unsigned short* __restrict__ W,
                                               const float* __restrict__ bias,
                                               const float* __restrict__ skip,
                                               float* __restrict__ h_out,
                                               unsigned short* __restrict__ hs_out,
                                               float* __restrict__ sum_out,
                                               const float* __restrict__ add_src)
{
    __shared__ unsigned short s_cols[4][CAP];
    __shared__ unsigned short s_y[16 * GD];       // 8 KB, XOR-swizzled rows

    const int tid  = threadIdx.x;
    const int w    = tid >> 6;         // wave 0..3
    const int lane = tid & 63;
    const int quad = lane >> 4;
    const int l16  = lane & 15;
    const int rbase = blockIdx.x * 16; // block's 16 rows

    // ---- phase 1: each wave aggregates 4 rows ----
    unsigned short* sc = s_cols[w];
    for (int rr = 0; rr < 4; ++rr) {
        const int r = w * 4 + rr;            // local row 0..15
        const int i = rbase + r;
        const int n = cnt[i];
        const unsigned short* crow = col + (size_t)i * CAP;
        for (int t = lane; t < n; t += 64) sc[t] = crow[t];
        // wave-coherent staging: producer == consumer wave; no barrier.

        float e0a = 0.f, e1a = 0.f, e2a = 0.f, e3a = 0.f;
        float e0b = 0.f, e1b = 0.f, e2b = 0.f, e3b = 0.f;
        int t = 0;
        for (; t + 8 <= n; t += 8) {
            ushort4 ca = *(const ushort4*)(sc + t);
            ushort4 cb = *(const ushort4*)(sc + t + 4);
            u32x2 u0 = hsw[(uint32)ca.x * 64u + lane];
            u32x2 u1 = hsw[(uint32)ca.y * 64u + lane];
            u32x2 u2 = hsw[(uint32)ca.z * 64u + lane];
            u32x2 u3 = hsw[(uint32)ca.w * 64u + lane];
            u32x2 u4 = hsw[(uint32)cb.x * 64u + lane];
            u32x2 u5 = hsw[(uint32)cb.y * 64u + lane];
            u32x2 u6 = hsw[(uint32)cb.z * 64u + lane];
            u32x2 u7 = hsw[(uint32)cb.w * 64u + lane];
            e0a += __uint_as_float(u0[0] << 16); e1a += __uint_as_float(u0[0] & 0xffff0000u);
            e2a += __uint_as_float(u0[1] << 16); e3a += __uint_as_float(u0[1] & 0xffff0000u);
            e0b += __uint_as_float(u1[0] << 16); e1b += __uint_as_float(u1[0] & 0xffff0000u);
            e2b += __uint_as_float(u1[1] << 16); e3b += __uint_as_float(u1[1] & 0xffff0000u);
            e0a += __uint_as_float(u2[0] << 16); e1a += __uint_as_float(u2[0] & 0xffff0000u);
            e2a += __uint_as_float(u2[1] << 16); e3a += __uint_as_float(u2[1] & 0xffff0000u);
            e0b += __uint_as_float(u3[0] << 16); e1b += __uint_as_float(u3[0] & 0xffff0000u);
            e2b += __uint_as_float(u3[1] << 16); e3b += __uint_as_float(u3[1] & 0xffff0000u);
            e0a += __uint_as_float(u4[0] << 16); e1a += __uint_as_float(u4[0] & 0xffff0000u);
            e2a += __uint_as_float(u4[1] << 16); e3a += __uint_as_float(u4[1] & 0xffff0000u);
            e0b += __uint_as_float(u5[0] << 16); e1b += __uint_as_float(u5[0] & 0xffff0000u);
            e2b += __uint_as_float(u5[1] << 16); e3b += __uint_as_float(u5[1] & 0xffff0000u);
            e0a += __uint_as_float(u6[0] << 16); e1a += __uint_as_float(u6[0] & 0xffff0000u);
            e2a += __uint_as_float(u6[1] << 16); e3a += __uint_as_float(u6[1] & 0xffff0000u);
            e0b += __uint_as_float(u7[0] << 16); e1b += __uint_as_float(u7[0] & 0xffff0000u);
            e2b += __uint_as_float(u7[1] << 16); e3b += __uint_as_float(u7[1] & 0xffff0000u);
        }
        for (; t < n; ++t) {
            u32x2 u = hsw[(uint32)sc[t] * 64u + lane];
            e0a += __uint_as_float(u[0] << 16); e1a += __uint_as_float(u[0] & 0xffff0000u);
            e2a += __uint_as_float(u[1] << 16); e3a += __uint_as_float(u[1] & 0xffff0000u);
        }
        u32x2 us = hsw[(uint32)i * 64u + lane];   // self-loop (+I)
        e0b += __uint_as_float(us[0] << 16); e1b += __uint_as_float(us[0] & 0xffff0000u);
        e2b += __uint_as_float(us[1] << 16); e3b += __uint_as_float(us[1] & 0xffff0000u);

        const float dv = dinv[i];
        const float e0 = (e0a + e0b) * dv;
        const float e1 = (e1a + e1b) * dv;
        const float e2 = (e2a + e2b) * dv;
        const float e3 = (e3a + e3b) * dv;
        u32x2 rv;
        rv[0] = (uint32)f2bf(e0) | ((uint32)f2bf(e1) << 16);
        rv[1] = (uint32)f2bf(e2) | ((uint32)f2bf(e3) << 16);
        const uint32 ba = (uint32)r * 512u + (uint32)lane * 8u;
        *(u32x2*)((char*)s_y + (ba ^ ((uint32)(r & 7) << 4))) = rv;
    }
    __syncthreads();

    // ---- phase 2: GEMM. Wave computes rows rbase..rbase+15, cols [w*64, w*64+64) ----
    const int n0 = w * 64;
    frag_cd acc0 = {0.f,0.f,0.f,0.f}, acc1 = {0.f,0.f,0.f,0.f};
    frag_cd acc2 = {0.f,0.f,0.f,0.f}, acc3 = {0.f,0.f,0.f,0.f};

    const uint32 aoff = (uint32)l16 * 512u + (uint32)quad * 16u;
    const uint32 aX   = ((uint32)(l16 & 7)) << 4;
    const size_t bb0 = (size_t)(n0 +  0 + l16) * GD + quad * 8;
    const size_t bb1 = (size_t)(n0 + 16 + l16) * GD + quad * 8;
    const size_t bb2 = (size_t)(n0 + 32 + l16) * GD + quad * 8;
    const size_t bb3 = (size_t)(n0 + 48 + l16) * GD + quad * 8;

#pragma unroll
    for (int k0 = 0; k0 < GD; k0 += 32) {
        // XOR applied to the FULL offset (k0*2 carries bit 6, which aX flips)
        frag_ab a  = *(const frag_ab*)((const char*)s_y + ((aoff + (uint32)k0 * 2u) ^ aX));
        frag_ab b0 = *(const frag_ab*)(W + bb0 + k0);
        frag_ab b1 = *(const frag_ab*)(W + bb1 + k0);
        frag_ab b2 = *(const frag_ab*)(W + bb2 + k0);
        frag_ab b3 = *(const frag_ab*)(W + bb3 + k0);
        acc0 = __builtin_amdgcn_mfma_f32_16x16x32_bf16(a, b0, acc0, 0, 0, 0);
        acc1 = __builtin_amdgcn_mfma_f32_16x16x32_bf16(a, b1, acc1, 0, 0, 0);
        acc2 = __builtin_amdgcn_mfma_f32_16x16x32_bf16(a, b2, acc2, 0, 0, 0);
        acc3 = __builtin_amdgcn_mfma_f32_16x16x32_bf16(a, b3, acc3, 0, 0, 0);
    }

    const float bn0 = bias[n0 +  0 + l16];
    const float bn1 = bias[n0 + 16 + l16];
    const float bn2 = bias[n0 + 32 + l16];
    const float bn3 = bias[n0 + 48 + l16];

#pragma unroll
    for (int reg = 0; reg < 4; ++reg) {
        const int m = rbase + quad * 4 + reg;   // C/D row = quad*4+reg
        const float dvm = dinv[m];
        float v[4];
        v[0] = fmaxf(acc0[reg] + bn0, 0.f);
        v[1] = fmaxf(acc1[reg] + bn1, 0.f);
        v[2] = fmaxf(acc2[reg] + bn2, 0.f);
        v[3] = fmaxf(acc3[reg] + bn3, 0.f);
#pragma unroll
        for (int nt = 0; nt < 4; ++nt) {
            const size_t idx = (size_t)m * GD + n0 + nt * 16 + l16;
            const float x = v[nt];
            if (h_out)  h_out[idx] = x;
            if (hs_out) {
                float s = skip ? skip[idx] : 0.f;
                hs_out[idx] = f2bf(dvm * (x + s));
            }
            if (sum_out) sum_out[idx] = x + add_src[idx];
        }
    }
}

// ---------------------------------------------------------------------------
extern "C" void kernel_launch(void* const* d_in, const int* in_sizes, int n_in,
                              void* d_out, int out_size, void* d_ws, size_t ws_size,
                              hipStream_t stream)
{
    const float* g  = (const float*)d_in[0];
    const float* h  = (const float*)d_in[1];
    const float* Wd = (const float*)d_in[2];
    const float* bd = (const float*)d_in[3];
    const float* Wb = (const float*)d_in[4];
    const float* bb = (const float*)d_in[5];
    const float* Wu = (const float*)d_in[6];
    const float* bu = (const float*)d_in[7];
    float* out = (float*)d_out;

    char* ws = (char*)d_ws;
    float*          dinv = (float*)ws;                               // 32 KB
    int*            cnt  = (int*)(ws + 32 * 1024);                   // 32 KB
    unsigned short* col  = (unsigned short*)(ws + 64 * 1024);        // 5.24 MB
    size_t off = 64 * 1024 + (size_t)GN * CAP * sizeof(unsigned short);
    off = (off + 255) & ~(size_t)255;
    unsigned short* hs0 = (unsigned short*)(ws + off); off += (size_t)GN * GD * 2;  // 4 MB
    unsigned short* hs1 = (unsigned short*)(ws + off); off += (size_t)GN * GD * 2;  // 4 MB
    unsigned short* w_bf = (unsigned short*)(ws + off); off += (size_t)7 * GD * GD * 2; // 0.9 MB
    off = (off + 255) & ~(size_t)255;
    float* dbuf1 = (float*)(ws + off); off += (size_t)GN * GD * 4;   // 8 MB
    float* dbuf2 = (float*)(ws + off); off += (size_t)GN * GD * 4;   // 8 MB
    float* dbuf3 = (float*)(ws + off); off += (size_t)GN * GD * 4;   // 8 MB
    (void)ws_size; (void)in_sizes; (void)n_in; (void)out_size;

    const size_t ND = (size_t)GN * GD;
    const int WSZ = GD * GD;   // 65536 elements per weight matrix

    k_build<<<GN, 256, 0, stream>>>(g, col, cnt, dinv);
    k_prep<<<2496, 256, 0, stream>>>(h, dinv, hs0, Wd, Wb, Wu, w_bf);

    // down 0..2: h_out -> dbuf_i, hs ping-pong (no skip)
    k_layer<<<GN / 16, 256, 0, stream>>>((const u32x2*)hs0, col, cnt, dinv,
        w_bf + 0 * (size_t)WSZ, bd + 0 * GD, nullptr, dbuf1, hs1, nullptr, nullptr);
    k_layer<<<GN / 16, 256, 0, stream>>>((const u32x2*)hs1, col, cnt, dinv,
        w_bf + 1 * (size_t)WSZ, bd + 1 * GD, nullptr, dbuf2, hs0, nullptr, nullptr);
    k_layer<<<GN / 16, 256, 0, stream>>>((const u32x2*)hs0, col, cnt, dinv,
        w_bf + 2 * (size_t)WSZ, bd + 2 * GD, nullptr, dbuf3, hs1, nullptr, nullptr);

    // bottom: hs with skip = down_outs[2]
    k_layer<<<GN / 16, 256, 0, stream>>>((const u32x2*)hs1, col, cnt, dinv,
        w_bf + 3 * (size_t)WSZ, bb, dbuf3, nullptr, hs0, nullptr, nullptr);

    // up 0: out[0] = h5; next hs with skip = down_outs[1]
    k_layer<<<GN / 16, 256, 0, stream>>>((const u32x2*)hs0, col, cnt, dinv,
        w_bf + 4 * (size_t)WSZ, bu + 0 * GD, dbuf2, out + 0 * ND, hs1, nullptr, nullptr);
    // up 1: out[1] = h6; next hs with skip = down_outs[0]
    k_layer<<<GN / 16, 256, 0, stream>>>((const u32x2*)hs1, col, cnt, dinv,
        w_bf + 5 * (size_t)WSZ, bu + 1 * GD, dbuf1, out + 1 * ND, hs0, nullptr, nullptr);
    // up 2: out[2] = h7; out[3] = h7 + org_h
    k_layer<<<GN / 16, 256, 0, stream>>>((const u32x2*)hs0, col, cnt, dinv,
        w_bf + 6 * (size_t)WSZ, bu + 2 * GD, nullptr, out + 2 * ND, nullptr, out + 3 * ND, h);
}